// Round 1
// baseline (6096.297 us; speedup 1.0000x reference)
//
#include <hip/hip_runtime.h>
#include <hip/hip_bf16.h>
#include <math.h>

// Problem constants
#define NN 3000        // nodes
#define CD 64          // channels
#define BD 8           // batch
#define TD 10          // T
#define T0D 12         // T0
#define WD 8           // windows
#define BC 512         // B*C columns of adjacency GEMM
#define ADJ_LD 9000    // adj row stride
#define SLAB (NN*BC)   // per-w (and per-t) slab: 1,536,000 floats

__device__ __forceinline__ float sigm(float x) { return 1.0f / (1.0f + __expf(-x)); }

// xT[t][n][b*64+c] = data[b][t][n][c] + temb[t][c] + semb[n][c]
__global__ void prep_x(const float* __restrict__ data, const float* __restrict__ temb,
                       const float* __restrict__ semb, float* __restrict__ xT) {
    int i = blockIdx.x * 256 + threadIdx.x;          // (t,n,b,c4): 10*3000*8*16
    if (i >= TD * NN * BD * 16) return;
    int c0 = (i & 15) << 2;
    int b  = (i >> 4) & 7;
    int r  = i >> 7;                                  // t*3000+n
    int n  = r % NN;
    int t  = r / NN;
    float4 dv = *(const float4*)(data + (((long)(b * TD + t) * NN + n) << 6) + c0);
    float4 tv = *(const float4*)(temb + t * 64 + c0);
    float4 sv = *(const float4*)(semb + n * 64 + c0);
    float4 o;
    o.x = dv.x + tv.x + sv.x; o.y = dv.y + tv.y + sv.y;
    o.z = dv.z + tv.z + sv.z; o.w = dv.w + tv.w + sv.w;
    *(float4*)(xT + (long)r * BC + b * 64 + c0) = o;
}

// w1t[kt][c][o] = conv1_w[o][c][0][kt]; w2t likewise (kt<5)
__global__ void prep_w(const float* __restrict__ c1w, const float* __restrict__ c2w,
                       float* __restrict__ w1t, float* __restrict__ w2t) {
    int i = blockIdx.x * 256 + threadIdx.x;
    if (i < 3 * 8192) {
        int kt = i >> 13; int rem = i & 8191; int c = rem >> 7; int o = rem & 127;
        w1t[i] = c1w[(o * 64 + c) * 3 + kt];
    } else if (i < 8 * 8192) {
        int j = i - 3 * 8192;
        int kt = j >> 13; int rem = j & 8191; int c = rem >> 7; int o = rem & 127;
        w2t[j] = c2w[(o * 64 + c) * 5 + kt];
    }
}

// Batched (over w) GEMM: C[n][j] = sum_m A[n][colOff+m] * B[w*bws + m*512 + j]
// A = adj (3000 x 9000). 64x64 tile, 256 thr, 4x4/thread, K-tile 32.
__global__ __launch_bounds__(256) void gemm_adj(
    const float* __restrict__ A, int colOff, int K,
    const float* __restrict__ Bb, long bws,
    float* __restrict__ Cb, long cws)
{
    const int w  = blockIdx.z;
    const float* Bp = Bb + (long)w * bws;
    float* Cp = Cb + (long)w * cws;
    const int n0 = blockIdx.y * 64;
    const int j0 = blockIdx.x * 64;
    const int tid = threadIdx.x;
    const int tx = tid & 15, ty = tid >> 4;
    __shared__ float As[32][68];   // [k][row], padded (272B rows keep 16B align)
    __shared__ float Bs[32][68];   // [k][col]
    float acc[4][4] = {{0.f}};
    const int nkt = (K + 31) >> 5;
    for (int kt = 0; kt < nkt; ++kt) {
        const int k0 = kt << 5;
        // A tile: 64 rows x 32 k (coalesced along k, store transposed)
        #pragma unroll
        for (int p = 0; p < 2; ++p) {
            int r  = p * 32 + (tid >> 3);
            int kc = (tid & 7) << 2;
            int row = n0 + r; row = row < NN ? row : NN - 1;
            int kk = k0 + kc;
            const float* ap = A + (long)row * ADJ_LD + colOff + kk;
            float4 v;
            if (kk + 4 <= K) v = *(const float4*)ap;
            else {
                v.x = (kk + 0 < K) ? ap[0] : 0.f;
                v.y = (kk + 1 < K) ? ap[1] : 0.f;
                v.z = (kk + 2 < K) ? ap[2] : 0.f;
                v.w = (kk + 3 < K) ? ap[3] : 0.f;
            }
            As[kc + 0][r] = v.x; As[kc + 1][r] = v.y;
            As[kc + 2][r] = v.z; As[kc + 3][r] = v.w;
        }
        // B tile: 32 k x 64 j
        #pragma unroll
        for (int p = 0; p < 2; ++p) {
            int r  = p * 16 + (tid >> 4);
            int jc = (tid & 15) << 2;
            int m = k0 + r;
            float4 v = {0.f, 0.f, 0.f, 0.f};
            if (m < K) v = *(const float4*)(Bp + (long)m * BC + j0 + jc);
            *(float4*)&Bs[r][jc] = v;
        }
        __syncthreads();
        #pragma unroll
        for (int kk = 0; kk < 32; ++kk) {
            float4 a = *(const float4*)&As[kk][ty << 2];
            float4 b = *(const float4*)&Bs[kk][tx << 2];
            float av[4] = {a.x, a.y, a.z, a.w};
            float bv[4] = {b.x, b.y, b.z, b.w};
            #pragma unroll
            for (int ii = 0; ii < 4; ++ii)
                #pragma unroll
                for (int jj = 0; jj < 4; ++jj)
                    acc[ii][jj] = fmaf(av[ii], bv[jj], acc[ii][jj]);
        }
        __syncthreads();
    }
    #pragma unroll
    for (int ii = 0; ii < 4; ++ii) {
        int row = n0 + (ty << 2) + ii;
        if (row < NN) {
            float4 v = {acc[ii][0], acc[ii][1], acc[ii][2], acc[ii][3]};
            *(float4*)(Cp + (long)row * BC + j0 + (tx << 2)) = v;
        }
    }
}

// GLU: rows R=(n*8+b) within w. y = yd+ywing (64) -> z = y @ gw[w,k] + gb (128)
// d = z[:64]*sigmoid(z[64:]) written IN PLACE to yd; maxd updated.
__global__ __launch_bounds__(256) void glu_kernel(
    float* __restrict__ Y, const float* __restrict__ Ywing,
    const float* __restrict__ gw_all, const float* __restrict__ gb_all,
    int kIdx, float* __restrict__ maxd)
{
    const int w = blockIdx.y;
    float* Yp = Y + (long)w * SLAB;
    const float* Wp = Ywing + (long)w * SLAB;
    float* Mp = maxd + (long)w * SLAB;
    const float* gw = gw_all + ((long)(w * 3 + kIdx) << 13);
    const float* gb = gb_all + (w * 3 + kIdx) * 128;
    const int r0 = blockIdx.x * 64;                  // rows per w: 24000 = 375*64
    const int tid = threadIdx.x;
    const int tx = tid & 15, ty = tid >> 4;
    __shared__ float As[64][68];                      // [c][row]
    __shared__ float Bs[64][132];                     // [c][o]
    #pragma unroll
    for (int p = 0; p < 4; ++p) {
        int r = p * 16 + ty;
        int c0 = tx << 2;
        long off = (long)(r0 + r) * 64 + c0;
        float4 a  = *(const float4*)(Yp + off);
        float4 wv = *(const float4*)(Wp + off);
        As[c0 + 0][r] = a.x + wv.x; As[c0 + 1][r] = a.y + wv.y;
        As[c0 + 2][r] = a.z + wv.z; As[c0 + 3][r] = a.w + wv.w;
    }
    #pragma unroll
    for (int p = 0; p < 8; ++p) {
        int r = p * 8 + (tid >> 5);
        int o0 = (tid & 31) << 2;
        *(float4*)&Bs[r][o0] = *(const float4*)(gw + r * 128 + o0);
    }
    __syncthreads();
    float acc[4][8] = {{0.f}};
    #pragma unroll 16
    for (int kk = 0; kk < 64; ++kk) {
        float4 a  = *(const float4*)&As[kk][ty << 2];
        float4 bl = *(const float4*)&Bs[kk][tx << 2];
        float4 br = *(const float4*)&Bs[kk][(tx << 2) + 64];
        float av[4]  = {a.x, a.y, a.z, a.w};
        float blv[4] = {bl.x, bl.y, bl.z, bl.w};
        float brv[4] = {br.x, br.y, br.z, br.w};
        #pragma unroll
        for (int ii = 0; ii < 4; ++ii)
            #pragma unroll
            for (int jj = 0; jj < 4; ++jj) {
                acc[ii][jj]     = fmaf(av[ii], blv[jj], acc[ii][jj]);
                acc[ii][jj + 4] = fmaf(av[ii], brv[jj], acc[ii][jj + 4]);
            }
    }
    const int c0 = tx << 2;
    #pragma unroll
    for (int ii = 0; ii < 4; ++ii) {
        int r = r0 + (ty << 2) + ii;
        long off = (long)r * 64 + c0;
        float4 dv;
        {
            float zl, zr;
            zl = acc[ii][0] + gb[c0 + 0]; zr = acc[ii][4] + gb[c0 + 64 + 0]; dv.x = zl * sigm(zr);
            zl = acc[ii][1] + gb[c0 + 1]; zr = acc[ii][5] + gb[c0 + 64 + 1]; dv.y = zl * sigm(zr);
            zl = acc[ii][2] + gb[c0 + 2]; zr = acc[ii][6] + gb[c0 + 64 + 2]; dv.z = zl * sigm(zr);
            zl = acc[ii][3] + gb[c0 + 3]; zr = acc[ii][7] + gb[c0 + 64 + 3]; dv.w = zl * sigm(zr);
        }
        *(float4*)(Yp + off) = dv;
        float4 mv = dv;
        if (kIdx > 0) {
            float4 old = *(const float4*)(Mp + off);
            mv.x = fmaxf(old.x, dv.x); mv.y = fmaxf(old.y, dv.y);
            mv.z = fmaxf(old.z, dv.z); mv.w = fmaxf(old.w, dv.w);
        }
        *(float4*)(Mp + off) = mv;
    }
}

// Gated convs (both), writes data_res part directly to out[b][wt][n][c].
__global__ __launch_bounds__(256) void conv_gated(
    const float* __restrict__ data, const float* __restrict__ orig,
    const float* __restrict__ w1t, const float* __restrict__ w2t,
    const float* __restrict__ b1, const float* __restrict__ b2,
    float* __restrict__ out)
{
    const int b  = blockIdx.z;
    const int wt = blockIdx.y;
    const int n0 = blockIdx.x * 64;
    const int tid = threadIdx.x;
    const int tx = tid & 15, ty = tid >> 4;
    __shared__ float As[64][68];    // [c][node]
    __shared__ float Bs[64][132];   // [c][o]
    float acc1[4][8] = {{0.f}};
    float acc2[4][8] = {{0.f}};
    for (int ch = 0; ch < 8; ++ch) {
        const float* src; const float* wsrc;
        if (ch < 3) { src = data + ((long)(b * TD  + wt + ch)      * NN) * 64; wsrc = w1t + (ch << 13); }
        else        { src = orig + ((long)(b * T0D + wt + (ch-3)) * NN) * 64; wsrc = w2t + ((ch-3) << 13); }
        #pragma unroll
        for (int p = 0; p < 4; ++p) {
            int r = p * 16 + ty;
            int c0 = tx << 2;
            int n = n0 + r; n = n < NN ? n : NN - 1;
            float4 v = *(const float4*)(src + (long)n * 64 + c0);
            As[c0 + 0][r] = v.x; As[c0 + 1][r] = v.y;
            As[c0 + 2][r] = v.z; As[c0 + 3][r] = v.w;
        }
        #pragma unroll
        for (int p = 0; p < 8; ++p) {
            int r = p * 8 + (tid >> 5);
            int o0 = (tid & 31) << 2;
            *(float4*)&Bs[r][o0] = *(const float4*)(wsrc + r * 128 + o0);
        }
        __syncthreads();
        if (ch < 3) {
            #pragma unroll 16
            for (int kk = 0; kk < 64; ++kk) {
                float4 a  = *(const float4*)&As[kk][ty << 2];
                float4 bl = *(const float4*)&Bs[kk][tx << 2];
                float4 br = *(const float4*)&Bs[kk][(tx << 2) + 64];
                float av[4]  = {a.x, a.y, a.z, a.w};
                float blv[4] = {bl.x, bl.y, bl.z, bl.w};
                float brv[4] = {br.x, br.y, br.z, br.w};
                #pragma unroll
                for (int ii = 0; ii < 4; ++ii)
                    #pragma unroll
                    for (int jj = 0; jj < 4; ++jj) {
                        acc1[ii][jj]     = fmaf(av[ii], blv[jj], acc1[ii][jj]);
                        acc1[ii][jj + 4] = fmaf(av[ii], brv[jj], acc1[ii][jj + 4]);
                    }
            }
        } else {
            #pragma unroll 16
            for (int kk = 0; kk < 64; ++kk) {
                float4 a  = *(const float4*)&As[kk][ty << 2];
                float4 bl = *(const float4*)&Bs[kk][tx << 2];
                float4 br = *(const float4*)&Bs[kk][(tx << 2) + 64];
                float av[4]  = {a.x, a.y, a.z, a.w};
                float blv[4] = {bl.x, bl.y, bl.z, bl.w};
                float brv[4] = {br.x, br.y, br.z, br.w};
                #pragma unroll
                for (int ii = 0; ii < 4; ++ii)
                    #pragma unroll
                    for (int jj = 0; jj < 4; ++jj) {
                        acc2[ii][jj]     = fmaf(av[ii], blv[jj], acc2[ii][jj]);
                        acc2[ii][jj + 4] = fmaf(av[ii], brv[jj], acc2[ii][jj + 4]);
                    }
            }
        }
        __syncthreads();
    }
    const int c0 = tx << 2;
    #pragma unroll
    for (int ii = 0; ii < 4; ++ii) {
        int n = n0 + (ty << 2) + ii;
        if (n < NN) {
            float4 ov;
            float t1l, t1r, t2l, t2r;
            t1l = acc1[ii][0] + b1[c0+0]; t1r = acc1[ii][4] + b1[c0+64+0];
            t2l = acc2[ii][0] + b2[c0+0]; t2r = acc2[ii][4] + b2[c0+64+0];
            ov.x = sigm(t1l) * t1r + sigm(t2l) * t2r;
            t1l = acc1[ii][1] + b1[c0+1]; t1r = acc1[ii][5] + b1[c0+64+1];
            t2l = acc2[ii][1] + b2[c0+1]; t2r = acc2[ii][5] + b2[c0+64+1];
            ov.y = sigm(t1l) * t1r + sigm(t2l) * t2r;
            t1l = acc1[ii][2] + b1[c0+2]; t1r = acc1[ii][6] + b1[c0+64+2];
            t2l = acc2[ii][2] + b2[c0+2]; t2r = acc2[ii][6] + b2[c0+64+2];
            ov.z = sigm(t1l) * t1r + sigm(t2l) * t2r;
            t1l = acc1[ii][3] + b1[c0+3]; t1r = acc1[ii][7] + b1[c0+64+3];
            t2l = acc2[ii][3] + b2[c0+3]; t2r = acc2[ii][7] + b2[c0+64+3];
            ov.w = sigm(t1l) * t1r + sigm(t2l) * t2r;
            *(float4*)(out + ((long)(b * WD + wt) * NN + n) * 64 + c0) = ov;
        }
    }
}

// out[b][wt][n][c] += maxd[wt][(n*8+b)*64+c] + xT[wt+2][n][b*64+c]
__global__ void final_add(const float* __restrict__ maxd, const float* __restrict__ xT,
                          float* __restrict__ out) {
    int i = blockIdx.x * 256 + threadIdx.x;          // 8*8*3000*16
    if (i >= BD * WD * NN * 16) return;
    int c0 = (i & 15) << 2;
    int r  = i >> 4;                                  // (b*8+wt)*3000+n
    int n  = r % NN;
    int q  = r / NN;
    int wt = q & 7;
    int b  = q >> 3;
    float4 o = *(const float4*)(out + (long)r * 64 + c0);
    float4 m = *(const float4*)(maxd + (long)wt * SLAB + ((long)n * 8 + b) * 64 + c0);
    float4 x = *(const float4*)(xT + ((long)(wt + 2) * NN + n) * BC + b * 64 + c0);
    o.x += m.x + x.x; o.y += m.y + x.y; o.z += m.z + x.z; o.w += m.w + x.w;
    *(float4*)(out + (long)r * 64 + c0) = o;
}

extern "C" void kernel_launch(void* const* d_in, const int* in_sizes, int n_in,
                              void* d_out, int out_size, void* d_ws, size_t ws_size,
                              hipStream_t stream) {
    const float* orig = (const float*)d_in[0];
    const float* data = (const float*)d_in[1];
    const float* adj  = (const float*)d_in[2];
    const float* c1w  = (const float*)d_in[3];
    const float* c1b  = (const float*)d_in[4];
    const float* c2w  = (const float*)d_in[5];
    const float* c2b  = (const float*)d_in[6];
    const float* temb = (const float*)d_in[7];
    const float* semb = (const float*)d_in[8];
    const float* gw   = (const float*)d_in[9];
    const float* gb   = (const float*)d_in[10];
    float* out = (float*)d_out;

    float* ws    = (float*)d_ws;
    float* xT    = ws;                       // 15,360,000
    float* ywing = xT    + 15360000;         // 12,288,000
    float* yA    = ywing + 12288000;         // 12,288,000
    float* yB    = yA    + 12288000;         // 12,288,000
    float* maxd  = yB    + 12288000;         // 12,288,000
    float* w1t   = maxd  + 12288000;         // 24,576
    float* w2t   = w1t   + 24576;            // 40,960  (total ~258 MB)

    prep_x<<<dim3((TD * NN * BD * 16 + 255) / 256), 256, 0, stream>>>(data, temb, semb, xT);
    prep_w<<<dim3(256), 256, 0, stream>>>(c1w, c2w, w1t, w2t);
    conv_gated<<<dim3(47, WD, BD), 256, 0, stream>>>(data, orig, w1t, w2t, c1b, c2b, out);

    // wing: once. B = xT + w*SLAB spans slices w,w+1 (6000 contiguous rows)
    gemm_adj<<<dim3(8, 47, WD), 256, 0, stream>>>(adj, 0,    6000, xT,            (long)SLAB, ywing, (long)SLAB);
    // k=0: d0 is the xT view shifted by 2 slices
    gemm_adj<<<dim3(8, 47, WD), 256, 0, stream>>>(adj, 6000, 3000, xT + 2L*SLAB,  (long)SLAB, yA,    (long)SLAB);
    glu_kernel<<<dim3(375, WD), 256, 0, stream>>>(yA, ywing, gw, gb, 0, maxd);
    gemm_adj<<<dim3(8, 47, WD), 256, 0, stream>>>(adj, 6000, 3000, yA,            (long)SLAB, yB,    (long)SLAB);
    glu_kernel<<<dim3(375, WD), 256, 0, stream>>>(yB, ywing, gw, gb, 1, maxd);
    gemm_adj<<<dim3(8, 47, WD), 256, 0, stream>>>(adj, 6000, 3000, yB,            (long)SLAB, yA,    (long)SLAB);
    glu_kernel<<<dim3(375, WD), 256, 0, stream>>>(yA, ywing, gw, gb, 2, maxd);

    final_add<<<dim3((BD * WD * NN * 16 + 255) / 256), 256, 0, stream>>>(maxd, xT, out);
}

// Round 2
// 1426.763 us; speedup vs baseline: 4.2728x; 4.2728x over previous
//
#include <hip/hip_runtime.h>
#include <hip/hip_bf16.h>
#include <math.h>

#define NN 3000
#define KA 3008          // A-operand row stride (bf16 elems), k=node padded
#define KB 9024          // adj bf16 row stride
#define MY 3072          // Y fp32 row stride (padded node dim)
#define BD 8
#define TD 10
#define T0D 12
#define WD 8
#define TSLAB (512L*KA)  // bf16 elems per t-slab / d' slab
#define YSLAB (512L*MY)  // fp32 elems per Y slab
#define MSLAB (512L*KA)  // fp32 elems per maxd slab

typedef __attribute__((ext_vector_type(8))) short short8;
typedef __attribute__((ext_vector_type(4))) float floatx4;

__device__ __forceinline__ float sigm(float x) { return 1.0f / (1.0f + __expf(-x)); }
__device__ __forceinline__ ushort f2b(float f) {
    __hip_bfloat16 h = __float2bfloat16(f);
    return *reinterpret_cast<ushort*>(&h);
}
__device__ __forceinline__ void ld_lds16(const void* g, void* l) {
    __builtin_amdgcn_global_load_lds((const __attribute__((address_space(1))) unsigned int*)g,
                                     (__attribute__((address_space(3))) unsigned int*)l, 16, 0, 0);
}

// adj (3000x9000 f32) -> adjb (3072x9024 bf16), pads zero
__global__ void prep_adj(const float* __restrict__ adj, ushort* __restrict__ adjb) {
    long i = (long)blockIdx.x * 256 + threadIdx.x;   // 3072*2256 quads
    if (i >= 3072L * 2256) return;
    int r  = (int)(i / 2256);
    int c4 = (int)(i % 2256) * 4;
    ushort4 u = {0, 0, 0, 0};
    if (r < NN && c4 < 9000) {
        float4 v = *(const float4*)(adj + (long)r * 9000 + c4);
        u.x = f2b(v.x); u.y = f2b(v.y); u.z = f2b(v.z); u.w = f2b(v.w);
    }
    *(ushort4*)(adjb + (long)r * KB + c4) = u;
}

// xT2[t][b*64+c][m=node] bf16 = data+temb+semb, node-pad zeroed
__global__ __launch_bounds__(256) void prep_xt(
    const float* __restrict__ data, const float* __restrict__ temb,
    const float* __restrict__ semb, ushort* __restrict__ xT2)
{
    const int t = blockIdx.z, b = blockIdx.y;
    const int m0 = blockIdx.x * 64;
    const int tid = threadIdx.x;
    const int tx = tid & 15, ty = tid >> 4;
    __shared__ float T[64][68];
    #pragma unroll
    for (int p = 0; p < 4; ++p) {
        int nl = p * 16 + ty;
        int n = m0 + nl;
        int c4 = tx * 4;
        float4 v = {0.f, 0.f, 0.f, 0.f};
        if (n < NN) {
            float4 dv = *(const float4*)(data + ((long)(b * TD + t) * NN + n) * 64 + c4);
            float4 tv = *(const float4*)(temb + t * 64 + c4);
            float4 sv = *(const float4*)(semb + n * 64 + c4);
            v.x = dv.x + tv.x + sv.x; v.y = dv.y + tv.y + sv.y;
            v.z = dv.z + tv.z + sv.z; v.w = dv.w + tv.w + sv.w;
        }
        T[c4 + 0][nl] = v.x; T[c4 + 1][nl] = v.y;
        T[c4 + 2][nl] = v.z; T[c4 + 3][nl] = v.w;
    }
    __syncthreads();
    #pragma unroll
    for (int p = 0; p < 4; ++p) {
        int c = p * 16 + ty;
        int m4 = tx * 4;
        ushort4 u;
        u.x = f2b(T[c][m4 + 0]); u.y = f2b(T[c][m4 + 1]);
        u.z = f2b(T[c][m4 + 2]); u.w = f2b(T[c][m4 + 3]);
        *(ushort4*)(xT2 + ((long)t * 512 + b * 64 + c) * KA + m0 + m4) = u;
    }
}

// w1t[kt][c][o] / w2t[kt][c][o]
__global__ void prep_w(const float* __restrict__ c1w, const float* __restrict__ c2w,
                       float* __restrict__ w1t, float* __restrict__ w2t) {
    int i = blockIdx.x * 256 + threadIdx.x;
    if (i < 3 * 8192) {
        int kt = i >> 13; int rem = i & 8191; int c = rem >> 7; int o = rem & 127;
        w1t[i] = c1w[(o * 64 + c) * 3 + kt];
    } else if (i < 8 * 8192) {
        int j = i - 3 * 8192;
        int kt = j >> 13; int rem = j & 8191; int c = rem >> 7; int o = rem & 127;
        w2t[j] = c2w[(o * 64 + c) * 5 + kt];
    }
}

// MFMA GEMM: Y[w][j][m] = sum_seg sum_k A_seg[w][j][k] * adjb[m][colOff_seg + k]
// A rows j (512), k-contig stride KA; B = adjb rows m (3072), k-contig stride KB.
__global__ __launch_bounds__(256) void gemm_mfma(
    const ushort* __restrict__ A0, const ushort* __restrict__ A1, int nseg, long aW,
    const ushort* __restrict__ Badj, int colOff0, int colOff1,
    float* __restrict__ Y)
{
    const int w = blockIdx.z;
    const int m0 = blockIdx.x * 128;
    const int j0 = blockIdx.y * 128;
    const int tid = threadIdx.x;
    const int lane = tid & 63;
    const int wv = tid >> 6;
    __shared__ ushort lA[128 * 32];
    __shared__ ushort lB[128 * 32];
    floatx4 acc[4][4] = {};
    const int srow = wv * 16 + (lane >> 2);   // staging row within 64-row group
    const int kp8  = (lane & 3) * 8;          // staging k element offset
    const int wj = (wv >> 1) * 64, wm = (wv & 1) * 64;
    const int half = lane >> 4;               // 0..3 -> k quarter
    const int rsub = lane & 15;
    for (int seg = 0; seg < nseg; ++seg) {
        const ushort* Ab = (seg ? A1 : A0) + (long)w * aW;
        const ushort* Bp = Badj + (seg ? colOff1 : colOff0);
        for (int kt = 0; kt < 94; ++kt) {
            const int k0 = kt * 32;
            #pragma unroll
            for (int p = 0; p < 2; ++p) {
                const ushort* g = Ab + (long)(j0 + p * 64 + srow) * KA + k0 + kp8;
                ld_lds16(g, lA + p * 2048 + wv * 512);
            }
            #pragma unroll
            for (int p = 0; p < 2; ++p) {
                const ushort* g = Bp + (long)(m0 + p * 64 + srow) * KB + k0 + kp8;
                ld_lds16(g, lB + p * 2048 + wv * 512);
            }
            __syncthreads();
            short8 af[4], bf[4];
            #pragma unroll
            for (int i = 0; i < 4; ++i)
                af[i] = *(const short8*)(lA + (wj + i * 16 + rsub) * 32 + half * 8);
            #pragma unroll
            for (int i = 0; i < 4; ++i)
                bf[i] = *(const short8*)(lB + (wm + i * 16 + rsub) * 32 + half * 8);
            #pragma unroll
            for (int i = 0; i < 4; ++i)
                #pragma unroll
                for (int jj = 0; jj < 4; ++jj)
                    acc[i][jj] = __builtin_amdgcn_mfma_f32_16x16x32_bf16(af[i], bf[jj], acc[i][jj], 0, 0, 0);
            __syncthreads();
        }
    }
    float* Yp = Y + (long)w * YSLAB;
    #pragma unroll
    for (int i = 0; i < 4; ++i) {
        int jrow = j0 + wj + i * 16 + half * 4;
        #pragma unroll
        for (int jj = 0; jj < 4; ++jj) {
            int mcol = m0 + wm + jj * 16 + rsub;
            float* o = Yp + (long)jrow * MY + mcol;
            o[0L * MY] = acc[i][jj].x;
            o[1L * MY] = acc[i][jj].y;
            o[2L * MY] = acc[i][jj].z;
            o[3L * MY] = acc[i][jj].w;
        }
    }
}

// GLU in transposed space: per b, Z[o][m] = sum_c gw[c][o] * (Yd+Ywing)[b*64+c][m]
// d = Z_lo * sigm(Z_hi) -> dp (bf16, next GEMM A) + maxd (fp32, running max)
__global__ __launch_bounds__(256) void glu_t(
    const float* __restrict__ Yd, const float* __restrict__ Ywing,
    const float* __restrict__ gw_all, const float* __restrict__ gb_all,
    int kIdx, ushort* __restrict__ dp, float* __restrict__ maxd)
{
    const int w = blockIdx.y;
    const int m0 = blockIdx.x * 64;
    const int tid = threadIdx.x;
    const int tx = tid & 15, ty = tid >> 4;
    const float* Ydp = Yd + (long)w * YSLAB;
    const float* Ywp = Ywing + (long)w * YSLAB;
    ushort* dpp = dp + (long)w * TSLAB;
    float* mdp = maxd + (long)w * MSLAB;
    const float* gw = gw_all + (long)(w * 3 + kIdx) * 8192;
    const float* gb = gb_all + (w * 3 + kIdx) * 128;
    __shared__ float gws[64][132];
    __shared__ float Ys[64][68];
    #pragma unroll
    for (int p = 0; p < 8; ++p) {
        int r = p * 8 + (tid >> 5);
        int c0 = (tid & 31) * 4;
        *(float4*)&gws[r][c0] = *(const float4*)(gw + r * 128 + c0);
    }
    for (int b = 0; b < 8; ++b) {
        if (b) __syncthreads();
        #pragma unroll
        for (int p = 0; p < 4; ++p) {
            int c = p * 16 + ty;
            long off = (long)(b * 64 + c) * MY + m0 + tx * 4;
            float4 v1 = *(const float4*)(Ydp + off);
            float4 v2 = *(const float4*)(Ywp + off);
            Ys[c][tx * 4 + 0] = v1.x + v2.x;
            Ys[c][tx * 4 + 1] = v1.y + v2.y;
            Ys[c][tx * 4 + 2] = v1.z + v2.z;
            Ys[c][tx * 4 + 3] = v1.w + v2.w;
        }
        __syncthreads();
        float acc[8][4] = {{0.f}};
        for (int c = 0; c < 64; ++c) {
            float4 ym = *(const float4*)&Ys[c][tx * 4];
            #pragma unroll
            for (int p = 0; p < 8; ++p) {
                float a = gws[c][ty + p * 16];
                acc[p][0] = fmaf(a, ym.x, acc[p][0]);
                acc[p][1] = fmaf(a, ym.y, acc[p][1]);
                acc[p][2] = fmaf(a, ym.z, acc[p][2]);
                acc[p][3] = fmaf(a, ym.w, acc[p][3]);
            }
        }
        #pragma unroll
        for (int p = 0; p < 4; ++p) {
            int c = ty + p * 16;
            float bl = gb[c], br = gb[64 + c];
            long row = (long)(b * 64 + c) * KA + m0 + tx * 4;
            float d[4];
            #pragma unroll
            for (int q = 0; q < 4; ++q) {
                float zl = acc[p][q] + bl;
                float zr = acc[p + 4][q] + br;
                d[q] = zl * sigm(zr);
            }
            int mb = m0 + tx * 4;
            if (kIdx < 2) {
                ushort4 u;
                u.x = (mb + 0 < NN) ? f2b(d[0]) : (ushort)0;
                u.y = (mb + 1 < NN) ? f2b(d[1]) : (ushort)0;
                u.z = (mb + 2 < NN) ? f2b(d[2]) : (ushort)0;
                u.w = (mb + 3 < NN) ? f2b(d[3]) : (ushort)0;
                *(ushort4*)(dpp + row) = u;
            }
            if (kIdx == 0) {
                float4 m4 = {d[0], d[1], d[2], d[3]};
                *(float4*)(mdp + row) = m4;
            } else {
                float4 old = *(const float4*)(mdp + row);
                float4 m4;
                m4.x = fmaxf(old.x, d[0]); m4.y = fmaxf(old.y, d[1]);
                m4.z = fmaxf(old.z, d[2]); m4.w = fmaxf(old.w, d[3]);
                *(float4*)(mdp + row) = m4;
            }
        }
    }
}

// Gated convs (both), writes data_res part directly to out[b][wt][n][c].
__global__ __launch_bounds__(256) void conv_gated(
    const float* __restrict__ data, const float* __restrict__ orig,
    const float* __restrict__ w1t, const float* __restrict__ w2t,
    const float* __restrict__ b1, const float* __restrict__ b2,
    float* __restrict__ out)
{
    const int b  = blockIdx.z;
    const int wt = blockIdx.y;
    const int n0 = blockIdx.x * 64;
    const int tid = threadIdx.x;
    const int tx = tid & 15, ty = tid >> 4;
    __shared__ float As[64][68];
    __shared__ float Bs[64][132];
    float acc1[4][8] = {{0.f}};
    float acc2[4][8] = {{0.f}};
    for (int ch = 0; ch < 8; ++ch) {
        const float* src; const float* wsrc;
        if (ch < 3) { src = data + ((long)(b * TD  + wt + ch)       * NN) * 64; wsrc = w1t + (ch << 13); }
        else        { src = orig + ((long)(b * T0D + wt + (ch - 3)) * NN) * 64; wsrc = w2t + ((ch - 3) << 13); }
        #pragma unroll
        for (int p = 0; p < 4; ++p) {
            int r = p * 16 + ty;
            int c0 = tx << 2;
            int n = n0 + r; n = n < NN ? n : NN - 1;
            float4 v = *(const float4*)(src + (long)n * 64 + c0);
            As[c0 + 0][r] = v.x; As[c0 + 1][r] = v.y;
            As[c0 + 2][r] = v.z; As[c0 + 3][r] = v.w;
        }
        #pragma unroll
        for (int p = 0; p < 8; ++p) {
            int r = p * 8 + (tid >> 5);
            int o0 = (tid & 31) << 2;
            *(float4*)&Bs[r][o0] = *(const float4*)(wsrc + r * 128 + o0);
        }
        __syncthreads();
        float (*acc)[8] = (ch < 3) ? acc1 : acc2;
        #pragma unroll 16
        for (int kk = 0; kk < 64; ++kk) {
            float4 a  = *(const float4*)&As[kk][ty << 2];
            float4 bl = *(const float4*)&Bs[kk][tx << 2];
            float4 br = *(const float4*)&Bs[kk][(tx << 2) + 64];
            float av[4]  = {a.x, a.y, a.z, a.w};
            float blv[4] = {bl.x, bl.y, bl.z, bl.w};
            float brv[4] = {br.x, br.y, br.z, br.w};
            #pragma unroll
            for (int ii = 0; ii < 4; ++ii)
                #pragma unroll
                for (int jj = 0; jj < 4; ++jj) {
                    acc[ii][jj]     = fmaf(av[ii], blv[jj], acc[ii][jj]);
                    acc[ii][jj + 4] = fmaf(av[ii], brv[jj], acc[ii][jj + 4]);
                }
        }
        __syncthreads();
    }
    const int c0 = tx << 2;
    #pragma unroll
    for (int ii = 0; ii < 4; ++ii) {
        int n = n0 + (ty << 2) + ii;
        if (n < NN) {
            float4 ov;
            float t1l, t1r, t2l, t2r;
            t1l = acc1[ii][0] + b1[c0+0]; t1r = acc1[ii][4] + b1[c0+64+0];
            t2l = acc2[ii][0] + b2[c0+0]; t2r = acc2[ii][4] + b2[c0+64+0];
            ov.x = sigm(t1l) * t1r + sigm(t2l) * t2r;
            t1l = acc1[ii][1] + b1[c0+1]; t1r = acc1[ii][5] + b1[c0+64+1];
            t2l = acc2[ii][1] + b2[c0+1]; t2r = acc2[ii][5] + b2[c0+64+1];
            ov.y = sigm(t1l) * t1r + sigm(t2l) * t2r;
            t1l = acc1[ii][2] + b1[c0+2]; t1r = acc1[ii][6] + b1[c0+64+2];
            t2l = acc2[ii][2] + b2[c0+2]; t2r = acc2[ii][6] + b2[c0+64+2];
            ov.z = sigm(t1l) * t1r + sigm(t2l) * t2r;
            t1l = acc1[ii][3] + b1[c0+3]; t1r = acc1[ii][7] + b1[c0+64+3];
            t2l = acc2[ii][3] + b2[c0+3]; t2r = acc2[ii][7] + b2[c0+64+3];
            ov.w = sigm(t1l) * t1r + sigm(t2l) * t2r;
            *(float4*)(out + ((long)(b * WD + wt) * NN + n) * 64 + c0) = ov;
        }
    }
}

// out[b][w][n][c] += maxd[w][b*64+c][n] (LDS transpose) + (data+temb+semb)[b][w+2][n][c]
__global__ __launch_bounds__(256) void final_t(
    const float* __restrict__ maxd, const float* __restrict__ data,
    const float* __restrict__ temb, const float* __restrict__ semb,
    float* __restrict__ out)
{
    const int w = blockIdx.z, b = blockIdx.y;
    const int m0 = blockIdx.x * 64;
    const int tid = threadIdx.x;
    const int tx = tid & 15, ty = tid >> 4;
    const float* mdp = maxd + (long)w * MSLAB;
    __shared__ float T[64][68];
    #pragma unroll
    for (int p = 0; p < 4; ++p) {
        int c = p * 16 + ty;
        float4 v = *(const float4*)(mdp + (long)(b * 64 + c) * KA + m0 + tx * 4);
        T[c][tx * 4 + 0] = v.x; T[c][tx * 4 + 1] = v.y;
        T[c][tx * 4 + 2] = v.z; T[c][tx * 4 + 3] = v.w;
    }
    __syncthreads();
    #pragma unroll
    for (int p = 0; p < 4; ++p) {
        int nl = p * 16 + ty;
        int n = m0 + nl;
        if (n < NN) {
            int c4 = tx * 4;
            long oidx = ((long)(b * WD + w) * NN + n) * 64 + c4;
            float4 o  = *(const float4*)(out + oidx);
            float4 dd = *(const float4*)(data + ((long)(b * TD + w + 2) * NN + n) * 64 + c4);
            float4 tv = *(const float4*)(temb + (w + 2) * 64 + c4);
            float4 sv = *(const float4*)(semb + n * 64 + c4);
            o.x += T[c4 + 0][nl] + dd.x + tv.x + sv.x;
            o.y += T[c4 + 1][nl] + dd.y + tv.y + sv.y;
            o.z += T[c4 + 2][nl] + dd.z + tv.z + sv.z;
            o.w += T[c4 + 3][nl] + dd.w + tv.w + sv.w;
            *(float4*)(out + oidx) = o;
        }
    }
}

extern "C" void kernel_launch(void* const* d_in, const int* in_sizes, int n_in,
                              void* d_out, int out_size, void* d_ws, size_t ws_size,
                              hipStream_t stream) {
    const float* orig = (const float*)d_in[0];
    const float* data = (const float*)d_in[1];
    const float* adj  = (const float*)d_in[2];
    const float* c1w  = (const float*)d_in[3];
    const float* c1b  = (const float*)d_in[4];
    const float* c2w  = (const float*)d_in[5];
    const float* c2b  = (const float*)d_in[6];
    const float* temb = (const float*)d_in[7];
    const float* semb = (const float*)d_in[8];
    const float* gw   = (const float*)d_in[9];
    const float* gb   = (const float*)d_in[10];
    float* out = (float*)d_out;

    char* ws = (char*)d_ws;
    ushort* adjb = (ushort*)ws;                          ws += 3072L * 9024 * 2;   // 55.44 MB
    ushort* xT2  = (ushort*)ws;                          ws += 10L * TSLAB * 2;    // 30.80 MB
    ushort* dpb  = (ushort*)ws;                          ws += 8L * TSLAB * 2;     // 24.64 MB
    float*  ywing = (float*)ws;                          ws += 8L * YSLAB * 4;     // 50.33 MB
    float*  yd    = (float*)ws;                          ws += 8L * YSLAB * 4;     // 50.33 MB
    float*  maxd  = (float*)ws;                          ws += 8L * MSLAB * 4;     // 49.28 MB
    float*  w1t   = (float*)ws;                          ws += 24576L * 4;
    float*  w2t   = (float*)ws;                          // total ~261.1 MB

    prep_adj<<<dim3(27072), 256, 0, stream>>>(adj, adjb);
    prep_xt<<<dim3(47, 8, 10), 256, 0, stream>>>(data, temb, semb, xT2);
    prep_w<<<dim3(256), 256, 0, stream>>>(c1w, c2w, w1t, w2t);
    conv_gated<<<dim3(47, 8, 8), 256, 0, stream>>>(data, orig, w1t, w2t, c1b, c2b, out);

    // wing (K = 2 segments of 3008): Ywing
    gemm_mfma<<<dim3(24, 4, 8), 256, 0, stream>>>(xT2, xT2 + TSLAB, 2, TSLAB, adjb, 0, 3000, ywing);
    // k=0: d0 = x slice w+2
    gemm_mfma<<<dim3(24, 4, 8), 256, 0, stream>>>(xT2 + 2 * TSLAB, xT2, 1, TSLAB, adjb, 6000, 0, yd);
    glu_t<<<dim3(47, 8), 256, 0, stream>>>(yd, ywing, gw, gb, 0, dpb, maxd);
    gemm_mfma<<<dim3(24, 4, 8), 256, 0, stream>>>(dpb, dpb, 1, TSLAB, adjb, 6000, 0, yd);
    glu_t<<<dim3(47, 8), 256, 0, stream>>>(yd, ywing, gw, gb, 1, dpb, maxd);
    gemm_mfma<<<dim3(24, 4, 8), 256, 0, stream>>>(dpb, dpb, 1, TSLAB, adjb, 6000, 0, yd);
    glu_t<<<dim3(47, 8), 256, 0, stream>>>(yd, ywing, gw, gb, 2, dpb, maxd);

    final_t<<<dim3(47, 8, 8), 256, 0, stream>>>(maxd, data, temb, semb, out);
}

// Round 3
// 1140.563 us; speedup vs baseline: 5.3450x; 1.2509x over previous
//
#include <hip/hip_runtime.h>
#include <hip/hip_bf16.h>
#include <math.h>

#define NN 3000
#define NP 3072          // padded node dim
#define KA 3008          // A-operand row stride (bf16 elems), k=node padded
#define KB 9024          // adj bf16 row stride
#define MY 3072          // Y fp32 row stride (padded node dim)
#define BD 8
#define TD 10
#define T0D 12
#define WD 8
#define TSLAB (512L*KA)  // bf16 elems per t-slab / d' slab
#define YSLAB (512L*MY)  // fp32 elems per Y slab
#define MSLAB (512L*KA)  // fp32 elems per maxd slab

typedef __attribute__((ext_vector_type(8))) short short8;
typedef __attribute__((ext_vector_type(4))) float floatx4;

__device__ __forceinline__ float sigm(float x) { return 1.0f / (1.0f + __expf(-x)); }
__device__ __forceinline__ ushort f2b(float f) {
    __hip_bfloat16 h = __float2bfloat16(f);
    return *reinterpret_cast<ushort*>(&h);
}
__device__ __forceinline__ void ld_lds16(const void* g, void* l) {
    __builtin_amdgcn_global_load_lds((const __attribute__((address_space(1))) unsigned int*)g,
                                     (__attribute__((address_space(3))) unsigned int*)l, 16, 0, 0);
}

// adj (3000x9000 f32) -> adjb (3072x9024 bf16), pads zero
__global__ void prep_adj(const float* __restrict__ adj, ushort* __restrict__ adjb) {
    long i = (long)blockIdx.x * 256 + threadIdx.x;   // 3072*2256 quads
    if (i >= 3072L * 2256) return;
    int r  = (int)(i / 2256);
    int c4 = (int)(i % 2256) * 4;
    ushort4 u = {0, 0, 0, 0};
    if (r < NN && c4 < 9000) {
        float4 v = *(const float4*)(adj + (long)r * 9000 + c4);
        u.x = f2b(v.x); u.y = f2b(v.y); u.z = f2b(v.z); u.w = f2b(v.w);
    }
    *(ushort4*)(adjb + (long)r * KB + c4) = u;
}

// xT2[t][b*64+c][m=node] bf16 = data+temb+semb, node-pad zeroed
__global__ __launch_bounds__(256) void prep_xt(
    const float* __restrict__ data, const float* __restrict__ temb,
    const float* __restrict__ semb, ushort* __restrict__ xT2)
{
    const int t = blockIdx.z, b = blockIdx.y;
    const int m0 = blockIdx.x * 64;
    const int tid = threadIdx.x;
    const int tx = tid & 15, ty = tid >> 4;
    __shared__ float T[64][68];
    #pragma unroll
    for (int p = 0; p < 4; ++p) {
        int nl = p * 16 + ty;
        int n = m0 + nl;
        int c4 = tx * 4;
        float4 v = {0.f, 0.f, 0.f, 0.f};
        if (n < NN) {
            float4 dv = *(const float4*)(data + ((long)(b * TD + t) * NN + n) * 64 + c4);
            float4 tv = *(const float4*)(temb + t * 64 + c4);
            float4 sv = *(const float4*)(semb + n * 64 + c4);
            v.x = dv.x + tv.x + sv.x; v.y = dv.y + tv.y + sv.y;
            v.z = dv.z + tv.z + sv.z; v.w = dv.w + tv.w + sv.w;
        }
        T[c4 + 0][nl] = v.x; T[c4 + 1][nl] = v.y;
        T[c4 + 2][nl] = v.z; T[c4 + 3][nl] = v.w;
    }
    __syncthreads();
    #pragma unroll
    for (int p = 0; p < 4; ++p) {
        int c = p * 16 + ty;
        int m4 = tx * 4;
        ushort4 u;
        u.x = f2b(T[c][m4 + 0]); u.y = f2b(T[c][m4 + 1]);
        u.z = f2b(T[c][m4 + 2]); u.w = f2b(T[c][m4 + 3]);
        *(ushort4*)(xT2 + ((long)t * 512 + b * 64 + c) * KA + m0 + m4) = u;
    }
}

// fp32 [b][t][3000][64] -> bf16 [b][t][3072][64], node pad zero
__global__ void prep_db(const float* __restrict__ src, ushort* __restrict__ dst, int Tt) {
    long i = (long)blockIdx.x * 256 + threadIdx.x;   // quads: 8*Tt*3072*16
    long tot = 8L * Tt * NP * 16;
    if (i >= tot) return;
    int c4 = (int)(i & 15) * 4;
    long r = i >> 4;                 // (b*Tt+t)*3072 + n
    int n = (int)(r % NP);
    long bt = r / NP;
    ushort4 u = {0, 0, 0, 0};
    if (n < NN) {
        float4 v = *(const float4*)(src + (bt * NN + n) * 64 + c4);
        u.x = f2b(v.x); u.y = f2b(v.y); u.z = f2b(v.z); u.w = f2b(v.w);
    }
    *(ushort4*)(dst + r * 64 + c4) = u;
}

// wb[r][k] bf16: r=permuted output channel (gating pairs in same lane), k=(slice,c)
// r: q=r>>6, jp=r&63; orig o = jp<32 ? q*32+jp : 64+q*32+(jp-32)
// k: s=k>>6 (slice 0..7), c=k&63; s<3 -> conv1_w[o][c][s], else conv2_w[o][c][s-3]
__global__ void prep_wb(const float* __restrict__ c1w, const float* __restrict__ c2w,
                        ushort* __restrict__ wb) {
    int i = blockIdx.x * 256 + threadIdx.x;
    if (i >= 128 * 512) return;
    int r = i >> 9, k = i & 511;
    int q = r >> 6, jp = r & 63;
    int o = (jp < 32) ? (q * 32 + jp) : (64 + q * 32 + (jp - 32));
    int s = k >> 6, c = k & 63;
    float v = (s < 3) ? c1w[(o * 64 + c) * 3 + s] : c2w[(o * 64 + c) * 5 + (s - 3)];
    wb[i] = f2b(v);
}

// MFMA GEMM: Y[w][j][m] = sum_seg sum_k A_seg[w][j][k] * adjb[m][colOff_seg + k]
__global__ __launch_bounds__(256) void gemm_mfma(
    const ushort* __restrict__ A0, const ushort* __restrict__ A1, int nseg, long aW,
    const ushort* __restrict__ Badj, int colOff0, int colOff1,
    float* __restrict__ Y)
{
    const int w = blockIdx.z;
    const int m0 = blockIdx.x * 128;
    const int j0 = blockIdx.y * 128;
    const int tid = threadIdx.x;
    const int lane = tid & 63;
    const int wv = tid >> 6;
    __shared__ ushort lA[128 * 32];
    __shared__ ushort lB[128 * 32];
    floatx4 acc[4][4] = {};
    const int srow = wv * 16 + (lane >> 2);
    const int kp8  = (lane & 3) * 8;
    const int wj = (wv >> 1) * 64, wm = (wv & 1) * 64;
    const int half = lane >> 4;
    const int rsub = lane & 15;
    for (int seg = 0; seg < nseg; ++seg) {
        const ushort* Ab = (seg ? A1 : A0) + (long)w * aW;
        const ushort* Bp = Badj + (seg ? colOff1 : colOff0);
        for (int kt = 0; kt < 94; ++kt) {
            const int k0 = kt * 32;
            #pragma unroll
            for (int p = 0; p < 2; ++p) {
                const ushort* g = Ab + (long)(j0 + p * 64 + srow) * KA + k0 + kp8;
                ld_lds16(g, lA + p * 2048 + wv * 512);
            }
            #pragma unroll
            for (int p = 0; p < 2; ++p) {
                const ushort* g = Bp + (long)(m0 + p * 64 + srow) * KB + k0 + kp8;
                ld_lds16(g, lB + p * 2048 + wv * 512);
            }
            __syncthreads();
            short8 af[4], bf[4];
            #pragma unroll
            for (int i = 0; i < 4; ++i)
                af[i] = *(const short8*)(lA + (wj + i * 16 + rsub) * 32 + half * 8);
            #pragma unroll
            for (int i = 0; i < 4; ++i)
                bf[i] = *(const short8*)(lB + (wm + i * 16 + rsub) * 32 + half * 8);
            #pragma unroll
            for (int i = 0; i < 4; ++i)
                #pragma unroll
                for (int jj = 0; jj < 4; ++jj)
                    acc[i][jj] = __builtin_amdgcn_mfma_f32_16x16x32_bf16(af[i], bf[jj], acc[i][jj], 0, 0, 0);
            __syncthreads();
        }
    }
    float* Yp = Y + (long)w * YSLAB;
    #pragma unroll
    for (int i = 0; i < 4; ++i) {
        int jrow = j0 + wj + i * 16 + half * 4;
        #pragma unroll
        for (int jj = 0; jj < 4; ++jj) {
            int mcol = m0 + wm + jj * 16 + rsub;
            float* o = Yp + (long)jrow * MY + mcol;
            o[0L * MY] = acc[i][jj].x;
            o[1L * MY] = acc[i][jj].y;
            o[2L * MY] = acc[i][jj].z;
            o[3L * MY] = acc[i][jj].w;
        }
    }
}

// Gated convs via MFMA. Per (b,wt): Z[n][o'] = sum_k A[n][k] * wb[o'][k], K=512.
// kt<6 -> acc1 (conv1, data slices), kt>=6 -> acc2 (conv2, orig slices).
// wb row permutation puts gating pair (c, c+64) at acc[?][jj] / acc[?][jj+2].
__global__ __launch_bounds__(256) void conv_mfma(
    const ushort* __restrict__ datab, const ushort* __restrict__ origb,
    const ushort* __restrict__ wb,
    const float* __restrict__ b1, const float* __restrict__ b2,
    float* __restrict__ out)
{
    const int b = blockIdx.y >> 3, wt = blockIdx.y & 7;
    const int n0 = blockIdx.x * 128;
    const int tid = threadIdx.x;
    const int lane = tid & 63;
    const int wv = tid >> 6;
    __shared__ ushort lA[128 * 32];
    __shared__ ushort lB[128 * 32];
    floatx4 acc1[4][4] = {};
    floatx4 acc2[4][4] = {};
    const int srow = wv * 16 + (lane >> 2);
    const int kp8  = (lane & 3) * 8;
    const int wj = (wv >> 1) * 64, wm = (wv & 1) * 64;
    const int half = lane >> 4;
    const int rsub = lane & 15;
    #pragma unroll
    for (int kt = 0; kt < 16; ++kt) {
        const int k0 = kt * 32;
        const int s = k0 >> 6;
        const int koff = k0 & 63;
        const ushort* Ab = (s < 3) ? datab + (long)(b * TD + wt + s) * NP * 64
                                   : origb + (long)(b * T0D + wt + (s - 3)) * NP * 64;
        #pragma unroll
        for (int p = 0; p < 2; ++p) {
            const ushort* g = Ab + (long)(n0 + p * 64 + srow) * 64 + koff + kp8;
            ld_lds16(g, lA + p * 2048 + wv * 512);
        }
        #pragma unroll
        for (int p = 0; p < 2; ++p) {
            const ushort* g = wb + (long)(p * 64 + srow) * 512 + k0 + kp8;
            ld_lds16(g, lB + p * 2048 + wv * 512);
        }
        __syncthreads();
        short8 af[4], bf[4];
        #pragma unroll
        for (int i = 0; i < 4; ++i)
            af[i] = *(const short8*)(lA + (wj + i * 16 + rsub) * 32 + half * 8);
        #pragma unroll
        for (int i = 0; i < 4; ++i)
            bf[i] = *(const short8*)(lB + (wm + i * 16 + rsub) * 32 + half * 8);
        if (kt < 6) {
            #pragma unroll
            for (int i = 0; i < 4; ++i)
                #pragma unroll
                for (int jj = 0; jj < 4; ++jj)
                    acc1[i][jj] = __builtin_amdgcn_mfma_f32_16x16x32_bf16(af[i], bf[jj], acc1[i][jj], 0, 0, 0);
        } else {
            #pragma unroll
            for (int i = 0; i < 4; ++i)
                #pragma unroll
                for (int jj = 0; jj < 4; ++jj)
                    acc2[i][jj] = __builtin_amdgcn_mfma_f32_16x16x32_bf16(af[i], bf[jj], acc2[i][jj], 0, 0, 0);
        }
        __syncthreads();
    }
    const int q = wv & 1;
    float* outp = out + (long)(b * WD + wt) * NN * 64;
    #pragma unroll
    for (int i = 0; i < 4; ++i) {
        const int nbase = n0 + wj + i * 16 + half * 4;
        #pragma unroll
        for (int jj = 0; jj < 2; ++jj) {
            const int ol = q * 32 + jj * 16 + rsub;           // output col c (0..63)
            const float bl1 = b1[ol], br1 = b1[64 + ol];
            const float bl2 = b2[ol], br2 = b2[64 + ol];
            float zl1[4] = {acc1[i][jj].x, acc1[i][jj].y, acc1[i][jj].z, acc1[i][jj].w};
            float zr1[4] = {acc1[i][jj+2].x, acc1[i][jj+2].y, acc1[i][jj+2].z, acc1[i][jj+2].w};
            float zl2[4] = {acc2[i][jj].x, acc2[i][jj].y, acc2[i][jj].z, acc2[i][jj].w};
            float zr2[4] = {acc2[i][jj+2].x, acc2[i][jj+2].y, acc2[i][jj+2].z, acc2[i][jj+2].w};
            #pragma unroll
            for (int r = 0; r < 4; ++r) {
                int n = nbase + r;
                if (n < NN) {
                    float ov = sigm(zl1[r] + bl1) * (zr1[r] + br1)
                             + sigm(zl2[r] + bl2) * (zr2[r] + br2);
                    outp[(long)n * 64 + ol] = ov;
                }
            }
        }
    }
}

// GLU in transposed space: per b, Z[o][m] = sum_c gw[c][o] * (Yd+Ywing)[b*64+c][m]
__global__ __launch_bounds__(256) void glu_t(
    const float* __restrict__ Yd, const float* __restrict__ Ywing,
    const float* __restrict__ gw_all, const float* __restrict__ gb_all,
    int kIdx, ushort* __restrict__ dp, float* __restrict__ maxd)
{
    const int w = blockIdx.y;
    const int m0 = blockIdx.x * 64;
    const int tid = threadIdx.x;
    const int tx = tid & 15, ty = tid >> 4;
    const float* Ydp = Yd + (long)w * YSLAB;
    const float* Ywp = Ywing + (long)w * YSLAB;
    ushort* dpp = dp + (long)w * TSLAB;
    float* mdp = maxd + (long)w * MSLAB;
    const float* gw = gw_all + (long)(w * 3 + kIdx) * 8192;
    const float* gb = gb_all + (w * 3 + kIdx) * 128;
    __shared__ float gws[64][132];
    __shared__ float Ys[64][68];
    #pragma unroll
    for (int p = 0; p < 8; ++p) {
        int r = p * 8 + (tid >> 5);
        int c0 = (tid & 31) * 4;
        *(float4*)&gws[r][c0] = *(const float4*)(gw + r * 128 + c0);
    }
    for (int b = 0; b < 8; ++b) {
        if (b) __syncthreads();
        #pragma unroll
        for (int p = 0; p < 4; ++p) {
            int c = p * 16 + ty;
            long off = (long)(b * 64 + c) * MY + m0 + tx * 4;
            float4 v1 = *(const float4*)(Ydp + off);
            float4 v2 = *(const float4*)(Ywp + off);
            Ys[c][tx * 4 + 0] = v1.x + v2.x;
            Ys[c][tx * 4 + 1] = v1.y + v2.y;
            Ys[c][tx * 4 + 2] = v1.z + v2.z;
            Ys[c][tx * 4 + 3] = v1.w + v2.w;
        }
        __syncthreads();
        float acc[8][4] = {{0.f}};
        for (int c = 0; c < 64; ++c) {
            float4 ym = *(const float4*)&Ys[c][tx * 4];
            #pragma unroll
            for (int p = 0; p < 8; ++p) {
                float a = gws[c][ty + p * 16];
                acc[p][0] = fmaf(a, ym.x, acc[p][0]);
                acc[p][1] = fmaf(a, ym.y, acc[p][1]);
                acc[p][2] = fmaf(a, ym.z, acc[p][2]);
                acc[p][3] = fmaf(a, ym.w, acc[p][3]);
            }
        }
        #pragma unroll
        for (int p = 0; p < 4; ++p) {
            int c = ty + p * 16;
            float bl = gb[c], br = gb[64 + c];
            long row = (long)(b * 64 + c) * KA + m0 + tx * 4;
            float d[4];
            #pragma unroll
            for (int q = 0; q < 4; ++q) {
                float zl = acc[p][q] + bl;
                float zr = acc[p + 4][q] + br;
                d[q] = zl * sigm(zr);
            }
            int mb = m0 + tx * 4;
            if (kIdx < 2) {
                ushort4 u;
                u.x = (mb + 0 < NN) ? f2b(d[0]) : (ushort)0;
                u.y = (mb + 1 < NN) ? f2b(d[1]) : (ushort)0;
                u.z = (mb + 2 < NN) ? f2b(d[2]) : (ushort)0;
                u.w = (mb + 3 < NN) ? f2b(d[3]) : (ushort)0;
                *(ushort4*)(dpp + row) = u;
            }
            if (kIdx == 0) {
                float4 m4 = {d[0], d[1], d[2], d[3]};
                *(float4*)(mdp + row) = m4;
            } else {
                float4 old = *(const float4*)(mdp + row);
                float4 m4;
                m4.x = fmaxf(old.x, d[0]); m4.y = fmaxf(old.y, d[1]);
                m4.z = fmaxf(old.z, d[2]); m4.w = fmaxf(old.w, d[3]);
                *(float4*)(mdp + row) = m4;
            }
        }
    }
}

// out[b][w][n][c] += maxd[w][b*64+c][n] (LDS transpose) + (data+temb+semb)[b][w+2][n][c]
__global__ __launch_bounds__(256) void final_t(
    const float* __restrict__ maxd, const float* __restrict__ data,
    const float* __restrict__ temb, const float* __restrict__ semb,
    float* __restrict__ out)
{
    const int w = blockIdx.z, b = blockIdx.y;
    const int m0 = blockIdx.x * 64;
    const int tid = threadIdx.x;
    const int tx = tid & 15, ty = tid >> 4;
    const float* mdp = maxd + (long)w * MSLAB;
    __shared__ float T[64][68];
    #pragma unroll
    for (int p = 0; p < 4; ++p) {
        int c = p * 16 + ty;
        float4 v = *(const float4*)(mdp + (long)(b * 64 + c) * KA + m0 + tx * 4);
        T[c][tx * 4 + 0] = v.x; T[c][tx * 4 + 1] = v.y;
        T[c][tx * 4 + 2] = v.z; T[c][tx * 4 + 3] = v.w;
    }
    __syncthreads();
    #pragma unroll
    for (int p = 0; p < 4; ++p) {
        int nl = p * 16 + ty;
        int n = m0 + nl;
        if (n < NN) {
            int c4 = tx * 4;
            long oidx = ((long)(b * WD + w) * NN + n) * 64 + c4;
            float4 o  = *(const float4*)(out + oidx);
            float4 dd = *(const float4*)(data + ((long)(b * TD + w + 2) * NN + n) * 64 + c4);
            float4 tv = *(const float4*)(temb + (w + 2) * 64 + c4);
            float4 sv = *(const float4*)(semb + n * 64 + c4);
            o.x += T[c4 + 0][nl] + dd.x + tv.x + sv.x;
            o.y += T[c4 + 1][nl] + dd.y + tv.y + sv.y;
            o.z += T[c4 + 2][nl] + dd.z + tv.z + sv.z;
            o.w += T[c4 + 3][nl] + dd.w + tv.w + sv.w;
            *(float4*)(out + oidx) = o;
        }
    }
}

extern "C" void kernel_launch(void* const* d_in, const int* in_sizes, int n_in,
                              void* d_out, int out_size, void* d_ws, size_t ws_size,
                              hipStream_t stream) {
    const float* orig = (const float*)d_in[0];
    const float* data = (const float*)d_in[1];
    const float* adj  = (const float*)d_in[2];
    const float* c1w  = (const float*)d_in[3];
    const float* c1b  = (const float*)d_in[4];
    const float* c2w  = (const float*)d_in[5];
    const float* c2b  = (const float*)d_in[6];
    const float* temb = (const float*)d_in[7];
    const float* semb = (const float*)d_in[8];
    const float* gw   = (const float*)d_in[9];
    const float* gb   = (const float*)d_in[10];
    float* out = (float*)d_out;

    char* ws = (char*)d_ws;
    ushort* adjb = (ushort*)ws;                          ws += 3072L * 9024 * 2;   // 55.44 MB
    ushort* xT2  = (ushort*)ws;                          ws += 10L * TSLAB * 2;    // 30.80 MB
    ushort* dpb  = (ushort*)ws;                          ws += 8L * TSLAB * 2;     // 24.64 MB
    float*  ywing = (float*)ws;                          ws += 8L * YSLAB * 4;     // 50.33 MB
    float*  yd    = (float*)ws;                          ws += 8L * YSLAB * 4;     // 50.33 MB
    float*  maxd  = (float*)ws;                          // 49.28 MB  (total ~260.8 MB)

    // Aliases (dead until overwritten by later kernels, in-stream order):
    ushort* wb    = (ushort*)ywing;   // 128 KB, consumed by conv_mfma before wing gemm
    ushort* datab = (ushort*)yd;      // 31.5 MB, consumed before d0 gemm writes yd
    ushort* origb = (ushort*)maxd;    // 37.7 MB, consumed before glu_t writes maxd

    prep_adj<<<dim3(27072), 256, 0, stream>>>(adj, adjb);
    prep_xt<<<dim3(47, 8, 10), 256, 0, stream>>>(data, temb, semb, xT2);
    prep_db<<<dim3(15360), 256, 0, stream>>>(data, datab, TD);
    prep_db<<<dim3(18432), 256, 0, stream>>>(orig, origb, T0D);
    prep_wb<<<dim3(256), 256, 0, stream>>>(c1w, c2w, wb);

    conv_mfma<<<dim3(24, 64), 256, 0, stream>>>(datab, origb, wb, c1b, c2b, out);

    gemm_mfma<<<dim3(24, 4, 8), 256, 0, stream>>>(xT2, xT2 + TSLAB, 2, TSLAB, adjb, 0, 3000, ywing);
    gemm_mfma<<<dim3(24, 4, 8), 256, 0, stream>>>(xT2 + 2 * TSLAB, xT2, 1, TSLAB, adjb, 6000, 0, yd);
    glu_t<<<dim3(47, 8), 256, 0, stream>>>(yd, ywing, gw, gb, 0, dpb, maxd);
    gemm_mfma<<<dim3(24, 4, 8), 256, 0, stream>>>(dpb, dpb, 1, TSLAB, adjb, 6000, 0, yd);
    glu_t<<<dim3(47, 8), 256, 0, stream>>>(yd, ywing, gw, gb, 1, dpb, maxd);
    gemm_mfma<<<dim3(24, 4, 8), 256, 0, stream>>>(dpb, dpb, 1, TSLAB, adjb, 6000, 0, yd);
    glu_t<<<dim3(47, 8), 256, 0, stream>>>(yd, ywing, gw, gb, 2, dpb, maxd);

    final_t<<<dim3(47, 8, 8), 256, 0, stream>>>(maxd, data, temb, semb, out);
}